// Round 1
// baseline (342.694 us; speedup 1.0000x reference)
//
#include <hip/hip_runtime.h>
#include <hip/hip_bf16.h>

// Problem dims (fixed): B=4, N=256, D=512, L=3
#define BB 4
#define NN 256
#define DD 512

using short8 = __attribute__((ext_vector_type(8))) short;
using f32x4  = __attribute__((ext_vector_type(4))) float;

__device__ __forceinline__ unsigned short f2bf(float f) {
    unsigned int u = __float_as_uint(f);
    unsigned int r = (u + 0x7fffu + ((u >> 16) & 1u)) >> 16;
    return (unsigned short)r;
}

// Stage a 128x64 bf16 tile from row-major global (stride elems) into LDS,
// XOR-swizzled: LDS slot s of row r holds global 16B-slot (s ^ (r&7)).
// Uses global_load_lds width 16 (linear LDS dest, pre-swizzled global src).
__device__ __forceinline__ void stage_tile(const unsigned short* src, int stride,
                                           short* dst, int tid) {
    int wave = tid >> 6, lane = tid & 63;
#pragma unroll
    for (int c = 0; c < 4; ++c) {
        int rbase = wave * 32 + c * 8;
        int row   = rbase + (lane >> 3);
        int slot  = (lane & 7) ^ (row & 7);
        const unsigned short* g = src + (size_t)row * stride + slot * 8;
        __builtin_amdgcn_global_load_lds(
            (const __attribute__((address_space(1))) void*)g,
            (__attribute__((address_space(3))) void*)(dst + rbase * 64),
            16, 0, 0);
    }
}

// Read an MFMA A/B fragment (16 rows x 32 k) from a swizzled [128][64] bf16 tile.
__device__ __forceinline__ short8 read_frag(const short* T, int rowBase, int k2) {
    int lane = threadIdx.x & 63;
    int row  = rowBase + (lane & 15);
    int slot = ((k2 * 4) + (lane >> 4)) ^ (row & 7);
    return *(const short8*)(T + row * 64 + slot * 8);
}

// ---------------- prep: fp32 -> bf16 weight conversion + h0 init ----------------
__global__ void prep_kernel(const float* __restrict__ x,
                            const float* __restrict__ gw, const float* __restrict__ tw,
                            const float* __restrict__ w0, const float* __restrict__ w1,
                            float* __restrict__ h0_f32, unsigned short* __restrict__ h0_bf,
                            unsigned short* __restrict__ wg_bf, unsigned short* __restrict__ wt_bf,
                            unsigned short* __restrict__ w0c_bf, unsigned short* __restrict__ w1_bf) {
    const int S_X = BB * NN * DD;          // 524288
    const int S_W = 3 * DD * DD;           // 786432
    const int S_W0 = 2 * DD * DD;          // 524288 (concat a|b parts)
    const int S_W1 = DD * DD;              // 262144
    int total = S_X + S_W + S_W + S_W0 + S_W1;
    for (int idx = blockIdx.x * blockDim.x + threadIdx.x; idx < total;
         idx += gridDim.x * blockDim.x) {
        int t = idx;
        if (t < S_X) { float v = x[t]; h0_f32[t] = v; h0_bf[t] = f2bf(v); continue; }
        t -= S_X;
        if (t < S_W) { wg_bf[t] = f2bf(gw[t]); continue; }
        t -= S_W;
        if (t < S_W) { wt_bf[t] = f2bf(tw[t]); continue; }
        t -= S_W;
        if (t < S_W0) {
            int e = t >> 9, d = t & 511;
            float v = (e < DD) ? w0[e * (2 * DD) + d] : w0[(e - DD) * (2 * DD) + DD + d];
            w0c_bf[t] = f2bf(v); continue;
        }
        t -= S_W0;
        w1_bf[t] = f2bf(w1[t]);
    }
}

// ---------------- highway layer: h' = g*relu(Wt h) + (1-g)*h ----------------
__global__ __launch_bounds__(256) void highway_kernel(
        const float* __restrict__ h_in, const unsigned short* __restrict__ hbf_in,
        const unsigned short* __restrict__ wg_bf, const unsigned short* __restrict__ wt_bf,
        const float* __restrict__ gb, const float* __restrict__ tb,
        float* __restrict__ h_out, unsigned short* __restrict__ hbf_out) {
    __shared__ short ht[128 * 64];
    __shared__ short wgt[128 * 64];
    __shared__ short wtt[128 * 64];
    int tid = threadIdx.x, lane = tid & 63, wave = tid >> 6;
    int mt = blockIdx.x >> 2, et = blockIdx.x & 3;
    int m0 = mt * 128, e0 = et * 128;
    int wm = wave >> 1, we = wave & 1;
    f32x4 gacc[4][4] = {}, tacc[4][4] = {};
    for (int ks = 0; ks < 8; ++ks) {
        int d0 = ks * 64;
        __syncthreads();
        stage_tile(hbf_in + (size_t)m0 * DD + d0, DD, ht, tid);
        stage_tile(wg_bf + (size_t)e0 * DD + d0, DD, wgt, tid);
        stage_tile(wt_bf + (size_t)e0 * DD + d0, DD, wtt, tid);
        __syncthreads();
#pragma unroll
        for (int k2 = 0; k2 < 2; ++k2) {
            short8 af[4], bg[4], bt[4];
#pragma unroll
            for (int f = 0; f < 4; ++f) af[f] = read_frag(ht, wm * 64 + f * 16, k2);
#pragma unroll
            for (int f = 0; f < 4; ++f) bg[f] = read_frag(wgt, we * 64 + f * 16, k2);
#pragma unroll
            for (int f = 0; f < 4; ++f) bt[f] = read_frag(wtt, we * 64 + f * 16, k2);
#pragma unroll
            for (int fm = 0; fm < 4; ++fm)
#pragma unroll
                for (int fn = 0; fn < 4; ++fn) {
                    gacc[fm][fn] = __builtin_amdgcn_mfma_f32_16x16x32_bf16(af[fm], bg[fn], gacc[fm][fn], 0, 0, 0);
                    tacc[fm][fn] = __builtin_amdgcn_mfma_f32_16x16x32_bf16(af[fm], bt[fn], tacc[fm][fn], 0, 0, 0);
                }
        }
    }
#pragma unroll
    for (int fm = 0; fm < 4; ++fm)
#pragma unroll
        for (int fn = 0; fn < 4; ++fn) {
            int e = e0 + we * 64 + fn * 16 + (lane & 15);
            float gbe = gb[e], tbe = tb[e];
#pragma unroll
            for (int r = 0; r < 4; ++r) {
                int m = m0 + wm * 64 + fm * 16 + (lane >> 4) * 4 + r;
                float g = 1.f / (1.f + __expf(-(gacc[fm][fn][r] + gbe)));
                float tv = tacc[fm][fn][r] + tbe; tv = tv > 0.f ? tv : 0.f;
                float ho = h_in[(size_t)m * DD + e];
                float hn = g * tv + (1.f - g) * ho;
                h_out[(size_t)m * DD + e] = hn;
                hbf_out[(size_t)m * DD + e] = f2bf(hn);
            }
        }
}

// ---------------- a/b projection: [1024,512] @ [512,1024(cat)] ----------------
__global__ __launch_bounds__(256) void ab_kernel(
        const unsigned short* __restrict__ hbf, const unsigned short* __restrict__ w0c_bf,
        const float* __restrict__ lw0_b,
        float* __restrict__ a_out, float* __restrict__ b_out) {
    __shared__ short ht[128 * 64];
    __shared__ short wt_[128 * 64];
    int tid = threadIdx.x, lane = tid & 63, wave = tid >> 6;
    int mt = blockIdx.x >> 3, et = blockIdx.x & 7;
    int m0 = mt * 128, e0 = et * 128;
    int wm = wave >> 1, we = wave & 1;
    f32x4 acc[4][4] = {};
    for (int ks = 0; ks < 8; ++ks) {
        __syncthreads();
        stage_tile(hbf + (size_t)m0 * DD + ks * 64, DD, ht, tid);
        stage_tile(w0c_bf + (size_t)e0 * DD + ks * 64, DD, wt_, tid);
        __syncthreads();
#pragma unroll
        for (int k2 = 0; k2 < 2; ++k2) {
            short8 af[4], bf_[4];
#pragma unroll
            for (int f = 0; f < 4; ++f) af[f] = read_frag(ht, wm * 64 + f * 16, k2);
#pragma unroll
            for (int f = 0; f < 4; ++f) bf_[f] = read_frag(wt_, we * 64 + f * 16, k2);
#pragma unroll
            for (int fm = 0; fm < 4; ++fm)
#pragma unroll
                for (int fn = 0; fn < 4; ++fn)
                    acc[fm][fn] = __builtin_amdgcn_mfma_f32_16x16x32_bf16(af[fm], bf_[fn], acc[fm][fn], 0, 0, 0);
        }
    }
#pragma unroll
    for (int fm = 0; fm < 4; ++fm)
#pragma unroll
        for (int fn = 0; fn < 4; ++fn) {
            int e = e0 + we * 64 + fn * 16 + (lane & 15);
#pragma unroll
            for (int r = 0; r < 4; ++r) {
                int m = m0 + wm * 64 + fm * 16 + (lane >> 4) * 4 + r;
                float v = acc[fm][fn][r];
                if (e < DD) a_out[(size_t)m * DD + e] = v + lw0_b[e];
                else        b_out[(size_t)m * DD + (e - DD)] = v;
            }
        }
}

// ---------------- fused pairwise kernel ----------------
// out[b,i,j] = sigmoid( sum_e relu( sum_d relu(a[b,i,d]+b[b,j,d])*W1[e,d] + b1[e] ) * wo[e] + bo )
__global__ __launch_bounds__(256) void pair_kernel(
        const float* __restrict__ a_f32, const float* __restrict__ b_f32,
        const unsigned short* __restrict__ w1_bf,
        const float* __restrict__ lw1_b, const float* __restrict__ lwo_w,
        const float* __restrict__ lwo_b, float* __restrict__ out) {
    __shared__ short zt[128 * 64];
    __shared__ short wt_[128 * 64];
    __shared__ float s_red[2 * 128];
    int tid = threadIdx.x, lane = tid & 63, wave = tid >> 6;
    int bid = blockIdx.x;
    int b  = bid >> 9;
    int i  = (bid >> 1) & 255;
    int j0 = (bid & 1) * 128;
    const float* arow = a_f32 + ((size_t)(b * NN + i)) * DD;
    const float* brow = b_f32 + ((size_t)(b * NN + j0)) * DD;
    s_red[tid] = 0.f;  // blockDim == 256 == 2*128
    int wm = wave >> 1, we = wave & 1;

    int s  = tid & 7;        // 16B slot within 64-col K chunk
    int rr = tid >> 3;       // 0..31 row-within-pass

    for (int ec = 0; ec < 4; ++ec) {
        f32x4 acc[4][4] = {};
        for (int ks = 0; ks < 8; ++ks) {
            int d0 = ks * 64;
            __syncthreads();
            // W1 tile: rows ec*128.., cols d0..
            stage_tile(w1_bf + (size_t)(ec * 128) * DD + d0, DD, wt_, tid);
            // z tile: computed, swizzled ds_write
            {
                int dl = d0 + s * 8;
                f32x4 alo = *(const f32x4*)(arow + dl);
                f32x4 ahi = *(const f32x4*)(arow + dl + 4);
#pragma unroll
                for (int p = 0; p < 4; ++p) {
                    int r = p * 32 + rr;
                    const float* bp = brow + (size_t)r * DD + dl;
                    f32x4 blo = *(const f32x4*)(bp);
                    f32x4 bhi = *(const f32x4*)(bp + 4);
                    short8 z;
#pragma unroll
                    for (int q = 0; q < 4; ++q) {
                        float v = alo[q] + blo[q]; v = v > 0.f ? v : 0.f;
                        z[q] = (short)f2bf(v);
                        float w2 = ahi[q] + bhi[q]; w2 = w2 > 0.f ? w2 : 0.f;
                        z[4 + q] = (short)f2bf(w2);
                    }
                    *(short8*)(zt + r * 64 + ((s ^ (r & 7)) * 8)) = z;
                }
            }
            __syncthreads();
#pragma unroll
            for (int k2 = 0; k2 < 2; ++k2) {
                short8 af[4], bf_[4];
#pragma unroll
                for (int f = 0; f < 4; ++f) af[f] = read_frag(zt, wm * 64 + f * 16, k2);
#pragma unroll
                for (int f = 0; f < 4; ++f) bf_[f] = read_frag(wt_, we * 64 + f * 16, k2);
#pragma unroll
                for (int fm = 0; fm < 4; ++fm)
#pragma unroll
                    for (int fn = 0; fn < 4; ++fn)
                        acc[fm][fn] = __builtin_amdgcn_mfma_f32_16x16x32_bf16(af[fm], bf_[fn], acc[fm][fn], 0, 0, 0);
            }
        }
        // chunk epilogue: relu(acc + b1)*wo, reduce over e
#pragma unroll
        for (int fm = 0; fm < 4; ++fm) {
            float red[4] = {0.f, 0.f, 0.f, 0.f};
#pragma unroll
            for (int fn = 0; fn < 4; ++fn) {
                int e = ec * 128 + we * 64 + fn * 16 + (lane & 15);
                float b1e = lw1_b[e], woe = lwo_w[e];
#pragma unroll
                for (int r = 0; r < 4; ++r) {
                    float v = acc[fm][fn][r] + b1e;
                    red[r] += (v > 0.f) ? v * woe : 0.f;
                }
            }
#pragma unroll
            for (int mask = 1; mask < 16; mask <<= 1)
#pragma unroll
                for (int r = 0; r < 4; ++r) red[r] += __shfl_xor(red[r], mask, 64);
            if ((lane & 15) == 0) {
#pragma unroll
                for (int r = 0; r < 4; ++r) {
                    int ml = wm * 64 + fm * 16 + (lane >> 4) * 4 + r;
                    s_red[we * 128 + ml] += red[r];   // owner-lane accumulate, no atomics
                }
            }
        }
    }
    __syncthreads();
    if (tid < 128) {
        float v = s_red[tid] + s_red[128 + tid] + lwo_b[0];
        out[((size_t)(b * NN + i)) * NN + j0 + tid] = 1.f / (1.f + __expf(-v));
    }
}

extern "C" void kernel_launch(void* const* d_in, const int* in_sizes, int n_in,
                              void* d_out, int out_size, void* d_ws, size_t ws_size,
                              hipStream_t stream) {
    const float* x    = (const float*)d_in[0];
    const float* gw   = (const float*)d_in[1];
    const float* gb   = (const float*)d_in[2];
    const float* tw   = (const float*)d_in[3];
    const float* tb   = (const float*)d_in[4];
    const float* w0   = (const float*)d_in[5];
    const float* w0b  = (const float*)d_in[6];
    const float* w1   = (const float*)d_in[7];
    const float* w1b_ = (const float*)d_in[8];
    const float* wo   = (const float*)d_in[9];
    const float* wob  = (const float*)d_in[10];
    float* out = (float*)d_out;

    char* w = (char*)d_ws;
    float* hA  = (float*)w;            w += (size_t)BB * NN * DD * 4;   // 2MB
    float* hB  = (float*)w;            w += (size_t)BB * NN * DD * 4;   // 2MB
    unsigned short* hbA = (unsigned short*)w; w += (size_t)BB * NN * DD * 2; // 1MB
    unsigned short* hbB = (unsigned short*)w; w += (size_t)BB * NN * DD * 2; // 1MB
    float* a_f = (float*)w;            w += (size_t)BB * NN * DD * 4;   // 2MB
    float* b_f = (float*)w;            w += (size_t)BB * NN * DD * 4;   // 2MB
    unsigned short* wg_bf  = (unsigned short*)w; w += (size_t)3 * DD * DD * 2; // 1.5MB
    unsigned short* wt_bf  = (unsigned short*)w; w += (size_t)3 * DD * DD * 2; // 1.5MB
    unsigned short* w0c_bf = (unsigned short*)w; w += (size_t)2 * DD * DD * 2; // 1MB
    unsigned short* w1_bf  = (unsigned short*)w; w += (size_t)DD * DD * 2;     // 0.5MB

    prep_kernel<<<1024, 256, 0, stream>>>(x, gw, tw, w0, w1, hA, hbA, wg_bf, wt_bf, w0c_bf, w1_bf);

    // highway layers (ping-pong): hA->hB->hA->hB
    highway_kernel<<<32, 256, 0, stream>>>(hA, hbA, wg_bf + 0 * DD * DD, wt_bf + 0 * DD * DD,
                                           gb + 0 * DD, tb + 0 * DD, hB, hbB);
    highway_kernel<<<32, 256, 0, stream>>>(hB, hbB, wg_bf + 1 * DD * DD, wt_bf + 1 * DD * DD,
                                           gb + 1 * DD, tb + 1 * DD, hA, hbA);
    highway_kernel<<<32, 256, 0, stream>>>(hA, hbA, wg_bf + 2 * DD * DD, wt_bf + 2 * DD * DD,
                                           gb + 2 * DD, tb + 2 * DD, hB, hbB);

    ab_kernel<<<64, 256, 0, stream>>>(hbB, w0c_bf, w0b, a_f, b_f);

    pair_kernel<<<2048, 256, 0, stream>>>(a_f, b_f, w1_bf, w1b_, wo, wob, out);
}

// Round 2
// 314.940 us; speedup vs baseline: 1.0881x; 1.0881x over previous
//
#include <hip/hip_runtime.h>
#include <hip/hip_bf16.h>

// Problem dims (fixed): B=4, N=256, D=512, L=3
#define BB 4
#define NN 256
#define DD 512

using short8  = __attribute__((ext_vector_type(8))) short;
using f32x4   = __attribute__((ext_vector_type(4))) float;
using uint32x4 = __attribute__((ext_vector_type(4))) unsigned int;

__device__ __forceinline__ unsigned short f2bf(float f) {
    unsigned int u = __float_as_uint(f);
    unsigned int r = (u + 0x7fffu + ((u >> 16) & 1u)) >> 16;
    return (unsigned short)r;
}

// packed f32->bf16 (RNE), 2 elems/instr
__device__ __forceinline__ unsigned cvtpk(float lo, float hi) {
    unsigned r;
    asm("v_cvt_pk_bf16_f32 %0, %1, %2" : "=v"(r) : "v"(lo), "v"(hi));
    return r;
}

// Stage a 128x64 bf16 tile from row-major global (stride elems) into LDS,
// XOR-swizzled: LDS slot s of row r holds global 16B-slot (s ^ (r&7)).
// NW = waves per block. global_load_lds width 16, linear LDS dest,
// pre-swizzled global source.
template <int NW>
__device__ __forceinline__ void stage_tile(const unsigned short* src, int stride,
                                           short* dst, int tid) {
    int wave = tid >> 6, lane = tid & 63;
#pragma unroll
    for (int c = 0; c < 16 / NW; ++c) {
        int rbase = (c * NW + wave) * 8;            // 8 rows per wave-issue
        int row   = rbase + (lane >> 3);
        int slot  = (lane & 7) ^ (row & 7);
        const unsigned short* g = src + (size_t)row * stride + slot * 8;
        __builtin_amdgcn_global_load_lds(
            (const __attribute__((address_space(1))) void*)g,
            (__attribute__((address_space(3))) void*)(dst + rbase * 64),
            16, 0, 0);
    }
}

// Read an MFMA A/B fragment (16 rows x 32 k) from a swizzled [128][64] bf16 tile.
__device__ __forceinline__ short8 read_frag(const short* T, int rowBase, int k2) {
    int lane = threadIdx.x & 63;
    int row  = rowBase + (lane & 15);
    int slot = ((k2 * 4) + (lane >> 4)) ^ (row & 7);
    return *(const short8*)(T + row * 64 + slot * 8);
}

// ---------------- prep: fp32 -> bf16 weight conversion + h0 init ----------------
__global__ void prep_kernel(const float* __restrict__ x,
                            const float* __restrict__ gw, const float* __restrict__ tw,
                            const float* __restrict__ w0, const float* __restrict__ w1,
                            float* __restrict__ h0_f32, unsigned short* __restrict__ h0_bf,
                            unsigned short* __restrict__ wg_bf, unsigned short* __restrict__ wt_bf,
                            unsigned short* __restrict__ w0c_bf, unsigned short* __restrict__ w1_bf) {
    const int S_X = BB * NN * DD;
    const int S_W = 3 * DD * DD;
    const int S_W0 = 2 * DD * DD;
    const int S_W1 = DD * DD;
    int total = S_X + S_W + S_W + S_W0 + S_W1;
    for (int idx = blockIdx.x * blockDim.x + threadIdx.x; idx < total;
         idx += gridDim.x * blockDim.x) {
        int t = idx;
        if (t < S_X) { float v = x[t]; h0_f32[t] = v; h0_bf[t] = f2bf(v); continue; }
        t -= S_X;
        if (t < S_W) { wg_bf[t] = f2bf(gw[t]); continue; }
        t -= S_W;
        if (t < S_W) { wt_bf[t] = f2bf(tw[t]); continue; }
        t -= S_W;
        if (t < S_W0) {
            int e = t >> 9, d = t & 511;
            float v = (e < DD) ? w0[e * (2 * DD) + d] : w0[(e - DD) * (2 * DD) + DD + d];
            w0c_bf[t] = f2bf(v); continue;
        }
        t -= S_W0;
        w1_bf[t] = f2bf(w1[t]);
    }
}

// ---------------- highway layer: h' = g*relu(Wt h) + (1-g)*h ----------------
__global__ __launch_bounds__(256) void highway_kernel(
        const float* __restrict__ h_in, const unsigned short* __restrict__ hbf_in,
        const unsigned short* __restrict__ wg_bf, const unsigned short* __restrict__ wt_bf,
        const float* __restrict__ gb, const float* __restrict__ tb,
        float* __restrict__ h_out, unsigned short* __restrict__ hbf_out) {
    __shared__ short ht[128 * 64];
    __shared__ short wgt[128 * 64];
    __shared__ short wtt[128 * 64];
    int tid = threadIdx.x, lane = tid & 63, wave = tid >> 6;
    int mt = blockIdx.x >> 2, et = blockIdx.x & 3;
    int m0 = mt * 128, e0 = et * 128;
    int wm = wave >> 1, we = wave & 1;
    f32x4 gacc[4][4] = {}, tacc[4][4] = {};
    for (int ks = 0; ks < 8; ++ks) {
        int d0 = ks * 64;
        __syncthreads();
        stage_tile<4>(hbf_in + (size_t)m0 * DD + d0, DD, ht, tid);
        stage_tile<4>(wg_bf + (size_t)e0 * DD + d0, DD, wgt, tid);
        stage_tile<4>(wt_bf + (size_t)e0 * DD + d0, DD, wtt, tid);
        __syncthreads();
#pragma unroll
        for (int k2 = 0; k2 < 2; ++k2) {
            short8 af[4], bg[4], bt[4];
#pragma unroll
            for (int f = 0; f < 4; ++f) af[f] = read_frag(ht, wm * 64 + f * 16, k2);
#pragma unroll
            for (int f = 0; f < 4; ++f) bg[f] = read_frag(wgt, we * 64 + f * 16, k2);
#pragma unroll
            for (int f = 0; f < 4; ++f) bt[f] = read_frag(wtt, we * 64 + f * 16, k2);
#pragma unroll
            for (int fm = 0; fm < 4; ++fm)
#pragma unroll
                for (int fn = 0; fn < 4; ++fn) {
                    gacc[fm][fn] = __builtin_amdgcn_mfma_f32_16x16x32_bf16(af[fm], bg[fn], gacc[fm][fn], 0, 0, 0);
                    tacc[fm][fn] = __builtin_amdgcn_mfma_f32_16x16x32_bf16(af[fm], bt[fn], tacc[fm][fn], 0, 0, 0);
                }
        }
    }
#pragma unroll
    for (int fm = 0; fm < 4; ++fm)
#pragma unroll
        for (int fn = 0; fn < 4; ++fn) {
            int e = e0 + we * 64 + fn * 16 + (lane & 15);
            float gbe = gb[e], tbe = tb[e];
#pragma unroll
            for (int r = 0; r < 4; ++r) {
                int m = m0 + wm * 64 + fm * 16 + (lane >> 4) * 4 + r;
                float g = 1.f / (1.f + __expf(-(gacc[fm][fn][r] + gbe)));
                float tv = tacc[fm][fn][r] + tbe; tv = tv > 0.f ? tv : 0.f;
                float ho = h_in[(size_t)m * DD + e];
                float hn = g * tv + (1.f - g) * ho;
                h_out[(size_t)m * DD + e] = hn;
                hbf_out[(size_t)m * DD + e] = f2bf(hn);
            }
        }
}

// ---------------- a/b projection: [1024,512] @ [512,1024(cat)] ----------------
__global__ __launch_bounds__(256) void ab_kernel(
        const unsigned short* __restrict__ hbf, const unsigned short* __restrict__ w0c_bf,
        const float* __restrict__ lw0_b,
        float* __restrict__ a_out, float* __restrict__ b_out) {
    __shared__ short ht[128 * 64];
    __shared__ short wt_[128 * 64];
    int tid = threadIdx.x, lane = tid & 63, wave = tid >> 6;
    int mt = blockIdx.x >> 3, et = blockIdx.x & 7;
    int m0 = mt * 128, e0 = et * 128;
    int wm = wave >> 1, we = wave & 1;
    f32x4 acc[4][4] = {};
    for (int ks = 0; ks < 8; ++ks) {
        __syncthreads();
        stage_tile<4>(hbf + (size_t)m0 * DD + ks * 64, DD, ht, tid);
        stage_tile<4>(w0c_bf + (size_t)e0 * DD + ks * 64, DD, wt_, tid);
        __syncthreads();
#pragma unroll
        for (int k2 = 0; k2 < 2; ++k2) {
            short8 af[4], bf_[4];
#pragma unroll
            for (int f = 0; f < 4; ++f) af[f] = read_frag(ht, wm * 64 + f * 16, k2);
#pragma unroll
            for (int f = 0; f < 4; ++f) bf_[f] = read_frag(wt_, we * 64 + f * 16, k2);
#pragma unroll
            for (int fm = 0; fm < 4; ++fm)
#pragma unroll
                for (int fn = 0; fn < 4; ++fn)
                    acc[fm][fn] = __builtin_amdgcn_mfma_f32_16x16x32_bf16(af[fm], bf_[fn], acc[fm][fn], 0, 0, 0);
        }
    }
#pragma unroll
    for (int fm = 0; fm < 4; ++fm)
#pragma unroll
        for (int fn = 0; fn < 4; ++fn) {
            int e = e0 + we * 64 + fn * 16 + (lane & 15);
#pragma unroll
            for (int r = 0; r < 4; ++r) {
                int m = m0 + wm * 64 + fm * 16 + (lane >> 4) * 4 + r;
                float v = acc[fm][fn][r];
                if (e < DD) a_out[(size_t)m * DD + e] = v + lw0_b[e];
                else        b_out[(size_t)m * DD + (e - DD)] = v;
            }
        }
}

// ---------------- fused pairwise kernel (v2) ----------------
// 512 threads (8 waves): wave grid 2(wm: 64 j) x 4(we: 32 e). Per block:
// j-tile 128, all E=512 via 4 E-chunks of 128. z = relu(a_i + b_j) computed
// ONCE into registers (64 VGPR/thread) at ec==0, replayed via ds_write for
// ec>=1. Single barrier per K-step, double-buffered zt/wt LDS.
#define COMPUTE_Z(K)                                                          \
    {                                                                         \
        const int dl_ = (K) * 64 + s * 8;                                     \
        f32x4 alo_ = *(const f32x4*)(arow + dl_);                             \
        f32x4 ahi_ = *(const f32x4*)(arow + dl_ + 4);                         \
        _Pragma("unroll")                                                     \
        for (int p_ = 0; p_ < 2; ++p_) {                                      \
            int r_ = p_ * 64 + rr;                                            \
            const float* bp_ = brow + (size_t)r_ * DD + dl_;                  \
            f32x4 blo_ = *(const f32x4*)bp_;                                  \
            f32x4 bhi_ = *(const f32x4*)(bp_ + 4);                            \
            float l0 = fmaxf(alo_[0] + blo_[0], 0.f);                         \
            float l1 = fmaxf(alo_[1] + blo_[1], 0.f);                         \
            float l2 = fmaxf(alo_[2] + blo_[2], 0.f);                         \
            float l3 = fmaxf(alo_[3] + blo_[3], 0.f);                         \
            float h0 = fmaxf(ahi_[0] + bhi_[0], 0.f);                         \
            float h1 = fmaxf(ahi_[1] + bhi_[1], 0.f);                         \
            float h2 = fmaxf(ahi_[2] + bhi_[2], 0.f);                         \
            float h3 = fmaxf(ahi_[3] + bhi_[3], 0.f);                         \
            zreg[K][p_][0] = cvtpk(l0, l1);                                   \
            zreg[K][p_][1] = cvtpk(l2, l3);                                   \
            zreg[K][p_][2] = cvtpk(h0, h1);                                   \
            zreg[K][p_][3] = cvtpk(h2, h3);                                   \
        }                                                                     \
    }

#define WRITE_Z(K, BUF)                                                       \
    {                                                                         \
        _Pragma("unroll")                                                     \
        for (int p_ = 0; p_ < 2; ++p_) {                                      \
            int r_ = p_ * 64 + rr;                                            \
            *(uint32x4*)((BUF) + r_ * 64 + ((s ^ (r_ & 7)) * 8)) =            \
                zreg[K][p_];                                                  \
        }                                                                     \
    }

__global__ __launch_bounds__(512, 2) void pair_kernel(
        const float* __restrict__ a_f32, const float* __restrict__ b_f32,
        const unsigned short* __restrict__ w1_bf,
        const float* __restrict__ lw1_b, const float* __restrict__ lwo_w,
        const float* __restrict__ lwo_b, float* __restrict__ out) {
    __shared__ short zt[2][128 * 64];
    __shared__ short wt_[2][128 * 64];
    __shared__ float s_red[4 * 128];
    int tid = threadIdx.x, lane = tid & 63, wave = tid >> 6;
    int bid = blockIdx.x;
    int bb = bid >> 9;
    int i  = (bid >> 1) & 255;
    int j0 = (bid & 1) * 128;
    const float* arow = a_f32 + ((size_t)(bb * NN + i)) * DD;
    const float* brow = b_f32 + ((size_t)(bb * NN + j0)) * DD;
    s_red[tid] = 0.f;                    // 512 == 4*128
    int wm = wave >> 2, we = wave & 3;   // wm: 0..1 (64 j), we: 0..3 (32 e)
    int s = tid & 7, rr = tid >> 3;      // rr: 0..63

    uint32x4 zreg[8][2];                 // cached z tile: [ks][p], 64 VGPRs

    // prologue: z for ks=0, write zt[0], stage W1 (ec=0,ks=0) -> wt[0]
    COMPUTE_Z(0)
    WRITE_Z(0, zt[0])
    stage_tile<8>(w1_bf, DD, wt_[0], tid);

    for (int ec = 0; ec < 4; ++ec) {
        f32x4 acc[4][2] = {};
#pragma unroll
        for (int ks = 0; ks < 8; ++ks) {
            __syncthreads();             // buffers [ks&1] ready (vmcnt+lgkm drained)
            // ---- prefetch next iteration into buffers [(ks+1)&1] ----
            if (!(ec == 3 && ks == 7)) {
                const int ksn = (ks + 1) & 7;           // compile-time per unrolled ks
                const int nb  = (ks + 1) & 1;
                int ecn = ec + (ks == 7 ? 1 : 0);
                if (ec == 0 && ks < 7) COMPUTE_Z(ksn)
                WRITE_Z(ksn, zt[nb])
                stage_tile<8>(w1_bf + (size_t)(ecn * 128) * DD + ksn * 64, DD,
                              wt_[nb], tid);
            }
            // ---- MFMA on current buffers ----
            const short* zc = zt[ks & 1];
            const short* wc = wt_[ks & 1];
#pragma unroll
            for (int k2 = 0; k2 < 2; ++k2) {
                short8 af[4], bfr[2];
#pragma unroll
                for (int f = 0; f < 4; ++f) af[f] = read_frag(zc, wm * 64 + f * 16, k2);
#pragma unroll
                for (int f = 0; f < 2; ++f) bfr[f] = read_frag(wc, we * 32 + f * 16, k2);
#pragma unroll
                for (int fm = 0; fm < 4; ++fm)
#pragma unroll
                    for (int fn = 0; fn < 2; ++fn)
                        acc[fm][fn] = __builtin_amdgcn_mfma_f32_16x16x32_bf16(
                            af[fm], bfr[fn], acc[fm][fn], 0, 0, 0);
            }
        }
        // ---- E-chunk epilogue: relu(acc+b1)*wo, reduce over e ----
#pragma unroll
        for (int fm = 0; fm < 4; ++fm) {
            float red[4] = {0.f, 0.f, 0.f, 0.f};
#pragma unroll
            for (int fn = 0; fn < 2; ++fn) {
                int e = ec * 128 + we * 32 + fn * 16 + (lane & 15);
                float b1e = lw1_b[e], woe = lwo_w[e];
#pragma unroll
                for (int r = 0; r < 4; ++r) {
                    float v = acc[fm][fn][r] + b1e;
                    red[r] += (v > 0.f) ? v * woe : 0.f;
                }
            }
#pragma unroll
            for (int mask = 1; mask < 16; mask <<= 1)
#pragma unroll
                for (int r = 0; r < 4; ++r) red[r] += __shfl_xor(red[r], mask, 64);
            if ((lane & 15) == 0) {
#pragma unroll
                for (int r = 0; r < 4; ++r) {
                    int ml = wm * 64 + fm * 16 + (lane >> 4) * 4 + r;
                    s_red[we * 128 + ml] += red[r];     // disjoint slots, no atomics
                }
            }
        }
    }
    __syncthreads();
    if (tid < 128) {
        float v = s_red[tid] + s_red[128 + tid] + s_red[256 + tid] +
                  s_red[384 + tid] + lwo_b[0];
        out[((size_t)(bb * NN + i)) * NN + j0 + tid] = 1.f / (1.f + __expf(-v));
    }
}

extern "C" void kernel_launch(void* const* d_in, const int* in_sizes, int n_in,
                              void* d_out, int out_size, void* d_ws, size_t ws_size,
                              hipStream_t stream) {
    const float* x    = (const float*)d_in[0];
    const float* gw   = (const float*)d_in[1];
    const float* gb   = (const float*)d_in[2];
    const float* tw   = (const float*)d_in[3];
    const float* tb   = (const float*)d_in[4];
    const float* w0   = (const float*)d_in[5];
    const float* w0b  = (const float*)d_in[6];
    const float* w1   = (const float*)d_in[7];
    const float* w1b_ = (const float*)d_in[8];
    const float* wo   = (const float*)d_in[9];
    const float* wob  = (const float*)d_in[10];
    float* out = (float*)d_out;

    char* w = (char*)d_ws;
    float* hA  = (float*)w;            w += (size_t)BB * NN * DD * 4;
    float* hB  = (float*)w;            w += (size_t)BB * NN * DD * 4;
    unsigned short* hbA = (unsigned short*)w; w += (size_t)BB * NN * DD * 2;
    unsigned short* hbB = (unsigned short*)w; w += (size_t)BB * NN * DD * 2;
    float* a_f = (float*)w;            w += (size_t)BB * NN * DD * 4;
    float* b_f = (float*)w;            w += (size_t)BB * NN * DD * 4;
    unsigned short* wg_bf  = (unsigned short*)w; w += (size_t)3 * DD * DD * 2;
    unsigned short* wt_bf  = (unsigned short*)w; w += (size_t)3 * DD * DD * 2;
    unsigned short* w0c_bf = (unsigned short*)w; w += (size_t)2 * DD * DD * 2;
    unsigned short* w1_bf  = (unsigned short*)w; w += (size_t)DD * DD * 2;

    prep_kernel<<<1024, 256, 0, stream>>>(x, gw, tw, w0, w1, hA, hbA, wg_bf, wt_bf, w0c_bf, w1_bf);

    highway_kernel<<<32, 256, 0, stream>>>(hA, hbA, wg_bf + 0 * DD * DD, wt_bf + 0 * DD * DD,
                                           gb + 0 * DD, tb + 0 * DD, hB, hbB);
    highway_kernel<<<32, 256, 0, stream>>>(hB, hbB, wg_bf + 1 * DD * DD, wt_bf + 1 * DD * DD,
                                           gb + 1 * DD, tb + 1 * DD, hA, hbA);
    highway_kernel<<<32, 256, 0, stream>>>(hA, hbA, wg_bf + 2 * DD * DD, wt_bf + 2 * DD * DD,
                                           gb + 2 * DD, tb + 2 * DD, hB, hbB);

    ab_kernel<<<64, 256, 0, stream>>>(hbB, w0c_bf, w0b, a_f, b_f);

    pair_kernel<<<2048, 512, 0, stream>>>(a_f, b_f, w1_bf, w1b_, wo, wob, out);
}

// Round 3
// 253.055 us; speedup vs baseline: 1.3542x; 1.2446x over previous
//
#include <hip/hip_runtime.h>
#include <hip/hip_bf16.h>

// Problem dims (fixed): B=4, N=256, D=512, L=3
#define BB 4
#define NN 256
#define DD 512

using short8   = __attribute__((ext_vector_type(8))) short;
using f32x4    = __attribute__((ext_vector_type(4))) float;
using uint32x4 = __attribute__((ext_vector_type(4))) unsigned int;

__device__ __forceinline__ unsigned short f2bf(float f) {
    unsigned int u = __float_as_uint(f);
    unsigned int r = (u + 0x7fffu + ((u >> 16) & 1u)) >> 16;
    return (unsigned short)r;
}

// packed f32->bf16 (RNE), 2 elems/instr
__device__ __forceinline__ unsigned cvtpk(float lo, float hi) {
    unsigned r;
    asm("v_cvt_pk_bf16_f32 %0, %1, %2" : "=v"(r) : "v"(lo), "v"(hi));
    return r;
}

// Stage a ROWSx64 bf16 tile from row-major global (stride elems) into LDS,
// XOR-swizzled: LDS slot s of row r holds global 16B-slot (s ^ (r&7)).
// global_load_lds width 16, linear LDS dest, pre-swizzled global source.
template <int ROWS, int NW>
__device__ __forceinline__ void stage_rows(const unsigned short* src, int stride,
                                           short* dst, int tid) {
    int wave = tid >> 6, lane = tid & 63;
#pragma unroll
    for (int c = 0; c < ROWS / (8 * NW); ++c) {
        int rbase = (c * NW + wave) * 8;
        int row   = rbase + (lane >> 3);
        int slot  = (lane & 7) ^ (row & 7);
        const unsigned short* g = src + (size_t)row * stride + slot * 8;
        __builtin_amdgcn_global_load_lds(
            (const __attribute__((address_space(1))) void*)g,
            (__attribute__((address_space(3))) void*)(dst + rbase * 64),
            16, 0, 0);
    }
}

// Read an MFMA A/B fragment (16 rows x 32 k) from a swizzled [ROWS][64] bf16 tile.
__device__ __forceinline__ short8 read_frag(const short* T, int rowBase, int k2) {
    int lane = threadIdx.x & 63;
    int row  = rowBase + (lane & 15);
    int slot = ((k2 * 4) + (lane >> 4)) ^ (row & 7);
    return *(const short8*)(T + row * 64 + slot * 8);
}

// ---------------- prep: fp32 -> bf16 weight conversion + h0 init ----------------
__global__ void prep_kernel(const float* __restrict__ x,
                            const float* __restrict__ gw, const float* __restrict__ tw,
                            const float* __restrict__ w0, const float* __restrict__ w1,
                            float* __restrict__ h0_f32, unsigned short* __restrict__ h0_bf,
                            unsigned short* __restrict__ wg_bf, unsigned short* __restrict__ wt_bf,
                            unsigned short* __restrict__ w0c_bf, unsigned short* __restrict__ w1_bf) {
    const int S_X = BB * NN * DD;
    const int S_W = 3 * DD * DD;
    const int S_W0 = 2 * DD * DD;
    const int S_W1 = DD * DD;
    int total = S_X + S_W + S_W + S_W0 + S_W1;
    for (int idx = blockIdx.x * blockDim.x + threadIdx.x; idx < total;
         idx += gridDim.x * blockDim.x) {
        int t = idx;
        if (t < S_X) { float v = x[t]; h0_f32[t] = v; h0_bf[t] = f2bf(v); continue; }
        t -= S_X;
        if (t < S_W) { wg_bf[t] = f2bf(gw[t]); continue; }
        t -= S_W;
        if (t < S_W) { wt_bf[t] = f2bf(tw[t]); continue; }
        t -= S_W;
        if (t < S_W0) {
            int e = t >> 9, d = t & 511;
            float v = (e < DD) ? w0[e * (2 * DD) + d] : w0[(e - DD) * (2 * DD) + DD + d];
            w0c_bf[t] = f2bf(v); continue;
        }
        t -= S_W0;
        w1_bf[t] = f2bf(w1[t]);
    }
}

// ---------------- highway layer: h' = g*relu(Wt h) + (1-g)*h ----------------
__global__ __launch_bounds__(256) void highway_kernel(
        const float* __restrict__ h_in, const unsigned short* __restrict__ hbf_in,
        const unsigned short* __restrict__ wg_bf, const unsigned short* __restrict__ wt_bf,
        const float* __restrict__ gb, const float* __restrict__ tb,
        float* __restrict__ h_out, unsigned short* __restrict__ hbf_out) {
    __shared__ short ht[128 * 64];
    __shared__ short wgt[128 * 64];
    __shared__ short wtt[128 * 64];
    int tid = threadIdx.x, lane = tid & 63, wave = tid >> 6;
    int mt = blockIdx.x >> 2, et = blockIdx.x & 3;
    int m0 = mt * 128, e0 = et * 128;
    int wm = wave >> 1, we = wave & 1;
    f32x4 gacc[4][4] = {}, tacc[4][4] = {};
    for (int ks = 0; ks < 8; ++ks) {
        int d0 = ks * 64;
        __syncthreads();
        stage_rows<128, 4>(hbf_in + (size_t)m0 * DD + d0, DD, ht, tid);
        stage_rows<128, 4>(wg_bf + (size_t)e0 * DD + d0, DD, wgt, tid);
        stage_rows<128, 4>(wt_bf + (size_t)e0 * DD + d0, DD, wtt, tid);
        __syncthreads();
#pragma unroll
        for (int k2 = 0; k2 < 2; ++k2) {
            short8 af[4], bg[4], bt[4];
#pragma unroll
            for (int f = 0; f < 4; ++f) af[f] = read_frag(ht, wm * 64 + f * 16, k2);
#pragma unroll
            for (int f = 0; f < 4; ++f) bg[f] = read_frag(wgt, we * 64 + f * 16, k2);
#pragma unroll
            for (int f = 0; f < 4; ++f) bt[f] = read_frag(wtt, we * 64 + f * 16, k2);
#pragma unroll
            for (int fm = 0; fm < 4; ++fm)
#pragma unroll
                for (int fn = 0; fn < 4; ++fn) {
                    gacc[fm][fn] = __builtin_amdgcn_mfma_f32_16x16x32_bf16(af[fm], bg[fn], gacc[fm][fn], 0, 0, 0);
                    tacc[fm][fn] = __builtin_amdgcn_mfma_f32_16x16x32_bf16(af[fm], bt[fn], tacc[fm][fn], 0, 0, 0);
                }
        }
    }
#pragma unroll
    for (int fm = 0; fm < 4; ++fm)
#pragma unroll
        for (int fn = 0; fn < 4; ++fn) {
            int e = e0 + we * 64 + fn * 16 + (lane & 15);
            float gbe = gb[e], tbe = tb[e];
#pragma unroll
            for (int r = 0; r < 4; ++r) {
                int m = m0 + wm * 64 + fm * 16 + (lane >> 4) * 4 + r;
                float g = 1.f / (1.f + __expf(-(gacc[fm][fn][r] + gbe)));
                float tv = tacc[fm][fn][r] + tbe; tv = tv > 0.f ? tv : 0.f;
                float ho = h_in[(size_t)m * DD + e];
                float hn = g * tv + (1.f - g) * ho;
                h_out[(size_t)m * DD + e] = hn;
                hbf_out[(size_t)m * DD + e] = f2bf(hn);
            }
        }
}

// ---------------- a/b projection: [1024,512] @ [512,1024(cat)] ----------------
__global__ __launch_bounds__(256) void ab_kernel(
        const unsigned short* __restrict__ hbf, const unsigned short* __restrict__ w0c_bf,
        const float* __restrict__ lw0_b,
        float* __restrict__ a_out, float* __restrict__ b_out) {
    __shared__ short ht[128 * 64];
    __shared__ short wt_[128 * 64];
    int tid = threadIdx.x, lane = tid & 63, wave = tid >> 6;
    int mt = blockIdx.x >> 3, et = blockIdx.x & 7;
    int m0 = mt * 128, e0 = et * 128;
    int wm = wave >> 1, we = wave & 1;
    f32x4 acc[4][4] = {};
    for (int ks = 0; ks < 8; ++ks) {
        __syncthreads();
        stage_rows<128, 4>(hbf + (size_t)m0 * DD + ks * 64, DD, ht, tid);
        stage_rows<128, 4>(w0c_bf + (size_t)e0 * DD + ks * 64, DD, wt_, tid);
        __syncthreads();
#pragma unroll
        for (int k2 = 0; k2 < 2; ++k2) {
            short8 af[4], bf_[4];
#pragma unroll
            for (int f = 0; f < 4; ++f) af[f] = read_frag(ht, wm * 64 + f * 16, k2);
#pragma unroll
            for (int f = 0; f < 4; ++f) bf_[f] = read_frag(wt_, we * 64 + f * 16, k2);
#pragma unroll
            for (int fm = 0; fm < 4; ++fm)
#pragma unroll
                for (int fn = 0; fn < 4; ++fn)
                    acc[fm][fn] = __builtin_amdgcn_mfma_f32_16x16x32_bf16(af[fm], bf_[fn], acc[fm][fn], 0, 0, 0);
        }
    }
#pragma unroll
    for (int fm = 0; fm < 4; ++fm)
#pragma unroll
        for (int fn = 0; fn < 4; ++fn) {
            int e = e0 + we * 64 + fn * 16 + (lane & 15);
#pragma unroll
            for (int r = 0; r < 4; ++r) {
                int m = m0 + wm * 64 + fm * 16 + (lane >> 4) * 4 + r;
                float v = acc[fm][fn][r];
                if (e < DD) a_out[(size_t)m * DD + e] = v + lw0_b[e];
                else        b_out[(size_t)m * DD + (e - DD)] = v;
            }
        }
}

// ---------------- fused pairwise kernel (v3: all-E, counted-vmcnt pipeline) ----
// 8 waves, each owns 128j x 64e (all E=512 in one pass, acc = 32 f32x4).
// 8 K-steps of BK=64. W1 double-buffered (2x64KB), staged via global_load_lds
// with vmcnt(14) counted waits (never 0 mid-loop). z (128x64, 16KB, single
// buffer) computed in-loop: global a/b loads issued early, math done under
// the MFMA phase (T14 split). s_red aliases zs after the loop.

#define Z_LOADS(K)                                                            \
    {                                                                         \
        const int dl_ = (K) * 64 + s * 8;                                     \
        alo = *(const f32x4*)(arow + dl_);                                    \
        ahi = *(const f32x4*)(arow + dl_ + 4);                                \
        const float* b0_ = brow + (size_t)rr * DD + dl_;                      \
        const float* b1_ = brow + (size_t)(64 + rr) * DD + dl_;               \
        b0lo = *(const f32x4*)b0_; b0hi = *(const f32x4*)(b0_ + 4);           \
        b1lo = *(const f32x4*)b1_; b1hi = *(const f32x4*)(b1_ + 4);           \
    }

#define Z_MATH()                                                              \
    {                                                                         \
        zw0[0] = cvtpk(fmaxf(alo[0] + b0lo[0], 0.f), fmaxf(alo[1] + b0lo[1], 0.f)); \
        zw0[1] = cvtpk(fmaxf(alo[2] + b0lo[2], 0.f), fmaxf(alo[3] + b0lo[3], 0.f)); \
        zw0[2] = cvtpk(fmaxf(ahi[0] + b0hi[0], 0.f), fmaxf(ahi[1] + b0hi[1], 0.f)); \
        zw0[3] = cvtpk(fmaxf(ahi[2] + b0hi[2], 0.f), fmaxf(ahi[3] + b0hi[3], 0.f)); \
        zw1[0] = cvtpk(fmaxf(alo[0] + b1lo[0], 0.f), fmaxf(alo[1] + b1lo[1], 0.f)); \
        zw1[1] = cvtpk(fmaxf(alo[2] + b1lo[2], 0.f), fmaxf(alo[3] + b1lo[3], 0.f)); \
        zw1[2] = cvtpk(fmaxf(ahi[0] + b1hi[0], 0.f), fmaxf(ahi[1] + b1hi[1], 0.f)); \
        zw1[3] = cvtpk(fmaxf(ahi[2] + b1hi[2], 0.f), fmaxf(ahi[3] + b1hi[3], 0.f)); \
    }

#define Z_WRITE()                                                             \
    {                                                                         \
        *(uint32x4*)(zs + rr * 64 + ((s ^ (rr & 7)) * 8)) = zw0;              \
        const int r1_ = 64 + rr;                                              \
        *(uint32x4*)(zs + r1_ * 64 + ((s ^ (r1_ & 7)) * 8)) = zw1;            \
    }

__global__ __launch_bounds__(512, 2) void pair_kernel(
        const float* __restrict__ a_f32, const float* __restrict__ b_f32,
        const unsigned short* __restrict__ w1_bf,
        const float* __restrict__ lw1_b, const float* __restrict__ lwo_w,
        const float* __restrict__ lwo_b, float* __restrict__ out) {
    __shared__ short ws[2][512 * 64];   // 128KB W1 double buffer
    __shared__ short zs[128 * 64];      // 16KB z tile; aliased as s_red after loop
    int tid = threadIdx.x, lane = tid & 63, wave = tid >> 6;
    int bid = blockIdx.x;
    int bb = bid >> 9, i = (bid >> 1) & 255, j0 = (bid & 1) * 128;
    const float* arow = a_f32 + (size_t)(bb * NN + i) * DD;
    const float* brow = b_f32 + (size_t)(bb * NN + j0) * DD;
    int s = tid & 7, rr = tid >> 3;     // rr: 0..63
    int we = wave;                       // e-slice owner: e in [we*64, we*64+64)

    f32x4 acc[8][4] = {};
    uint32x4 zw0, zw1;
    f32x4 alo, ahi, b0lo, b0hi, b1lo, b1hi;

    // ---- prologue: z[0] temps + W1[0] stage ----
    Z_LOADS(0)
    Z_MATH()
    stage_rows<512, 8>(w1_bf, DD, ws[0], tid);

#pragma unroll
    for (int k = 0; k < 8; ++k) {
        __builtin_amdgcn_s_barrier();        // prior step's LDS reads all done
        __builtin_amdgcn_sched_barrier(0);
        Z_WRITE()                            // z[k] from temps
        if (k < 7) {
            Z_LOADS(k + 1)                   // issue a/b early (consumed in Z_MATH below)
            stage_rows<512, 8>(w1_bf + (size_t)(k + 1) * 64, DD, ws[(k + 1) & 1], tid);
        }
        asm volatile("s_waitcnt lgkmcnt(0)" ::: "memory");   // z[k] visible
        if (k < 7) asm volatile("s_waitcnt vmcnt(14)" ::: "memory");  // W1[k] landed; 14 = 6 a/b + 8 stage in flight
        else       asm volatile("s_waitcnt vmcnt(0)" ::: "memory");
        __builtin_amdgcn_s_barrier();        // z[k] + W1[k] ready for everyone
        __builtin_amdgcn_sched_barrier(0);

        const short* wc = ws[k & 1];
#pragma unroll
        for (int k2 = 0; k2 < 2; ++k2) {
            short8 bfr[4];
#pragma unroll
            for (int f = 0; f < 4; ++f) bfr[f] = read_frag(wc, we * 64 + f * 16, k2);
#pragma unroll
            for (int fh = 0; fh < 2; ++fh) {
                short8 af[4];
#pragma unroll
                for (int f = 0; f < 4; ++f) af[f] = read_frag(zs, (fh * 4 + f) * 16, k2);
#pragma unroll
                for (int fm = 0; fm < 4; ++fm)
#pragma unroll
                    for (int fn = 0; fn < 4; ++fn)
                        acc[fh * 4 + fm][fn] = __builtin_amdgcn_mfma_f32_16x16x32_bf16(
                            af[fm], bfr[fn], acc[fh * 4 + fm][fn], 0, 0, 0);
            }
        }
        if (k < 7) Z_MATH()                  // z[k+1] temps, hidden under MFMA
    }

    // ---- epilogue: relu(acc+b1)*wo, reduce over all e ----
    __syncthreads();                         // zs reads done -> reuse as s_red
    float* s_red = (float*)zs;               // 8 waves x 128 j partials
#pragma unroll
    for (int fm = 0; fm < 8; ++fm) {
        float red[4] = {0.f, 0.f, 0.f, 0.f};
#pragma unroll
        for (int fn = 0; fn < 4; ++fn) {
            int e = we * 64 + fn * 16 + (lane & 15);
            float b1e = lw1_b[e], woe = lwo_w[e];
#pragma unroll
            for (int r = 0; r < 4; ++r) {
                float v = acc[fm][fn][r] + b1e;
                red[r] += (v > 0.f) ? v * woe : 0.f;
            }
        }
#pragma unroll
        for (int mask = 1; mask < 16; mask <<= 1)
#pragma unroll
            for (int r = 0; r < 4; ++r) red[r] += __shfl_xor(red[r], mask, 64);
        if ((lane & 15) == 0) {
#pragma unroll
            for (int r = 0; r < 4; ++r)
                s_red[we * 128 + fm * 16 + (lane >> 4) * 4 + r] = red[r];
        }
    }
    __syncthreads();
    if (tid < 128) {
        float v = lwo_b[0];
#pragma unroll
        for (int w8 = 0; w8 < 8; ++w8) v += s_red[w8 * 128 + tid];
        out[((size_t)(bb * NN + i)) * NN + j0 + tid] = 1.f / (1.f + __expf(-v));
    }
}

extern "C" void kernel_launch(void* const* d_in, const int* in_sizes, int n_in,
                              void* d_out, int out_size, void* d_ws, size_t ws_size,
                              hipStream_t stream) {
    const float* x    = (const float*)d_in[0];
    const float* gw   = (const float*)d_in[1];
    const float* gb   = (const float*)d_in[2];
    const float* tw   = (const float*)d_in[3];
    const float* tb   = (const float*)d_in[4];
    const float* w0   = (const float*)d_in[5];
    const float* w0b  = (const float*)d_in[6];
    const float* w1   = (const float*)d_in[7];
    const float* w1b_ = (const float*)d_in[8];
    const float* wo   = (const float*)d_in[9];
    const float* wob  = (const float*)d_in[10];
    float* out = (float*)d_out;

    char* w = (char*)d_ws;
    float* hA  = (float*)w;            w += (size_t)BB * NN * DD * 4;
    float* hB  = (float*)w;            w += (size_t)BB * NN * DD * 4;
    unsigned short* hbA = (unsigned short*)w; w += (size_t)BB * NN * DD * 2;
    unsigned short* hbB = (unsigned short*)w; w += (size_t)BB * NN * DD * 2;
    float* a_f = (float*)w;            w += (size_t)BB * NN * DD * 4;
    float* b_f = (float*)w;            w += (size_t)BB * NN * DD * 4;
    unsigned short* wg_bf  = (unsigned short*)w; w += (size_t)3 * DD * DD * 2;
    unsigned short* wt_bf  = (unsigned short*)w; w += (size_t)3 * DD * DD * 2;
    unsigned short* w0c_bf = (unsigned short*)w; w += (size_t)2 * DD * DD * 2;
    unsigned short* w1_bf  = (unsigned short*)w; w += (size_t)DD * DD * 2;

    prep_kernel<<<1024, 256, 0, stream>>>(x, gw, tw, w0, w1, hA, hbA, wg_bf, wt_bf, w0c_bf, w1_bf);

    highway_kernel<<<32, 256, 0, stream>>>(hA, hbA, wg_bf + 0 * DD * DD, wt_bf + 0 * DD * DD,
                                           gb + 0 * DD, tb + 0 * DD, hB, hbB);
    highway_kernel<<<32, 256, 0, stream>>>(hB, hbB, wg_bf + 1 * DD * DD, wt_bf + 1 * DD * DD,
                                           gb + 1 * DD, tb + 1 * DD, hA, hbA);
    highway_kernel<<<32, 256, 0, stream>>>(hA, hbA, wg_bf + 2 * DD * DD, wt_bf + 2 * DD * DD,
                                           gb + 2 * DD, tb + 2 * DD, hB, hbB);

    ab_kernel<<<64, 256, 0, stream>>>(hbB, w0c_bf, w0b, a_f, b_f);

    pair_kernel<<<2048, 512, 0, stream>>>(a_f, b_f, w1_bf, w1b_, wo, wob, out);
}

// Round 4
// 220.271 us; speedup vs baseline: 1.5558x; 1.1488x over previous
//
#include <hip/hip_runtime.h>
#include <hip/hip_bf16.h>

// Problem dims (fixed): B=4, N=256, D=512, L=3
#define BB 4
#define NN 256
#define DD 512

using short8   = __attribute__((ext_vector_type(8))) short;
using f32x4    = __attribute__((ext_vector_type(4))) float;
using uint32x4 = __attribute__((ext_vector_type(4))) unsigned int;

__device__ __forceinline__ unsigned short f2bf(float f) {
    unsigned int u = __float_as_uint(f);
    unsigned int r = (u + 0x7fffu + ((u >> 16) & 1u)) >> 16;
    return (unsigned short)r;
}

// packed f32->bf16 (RNE), 2 elems/instr
__device__ __forceinline__ unsigned cvtpk(float lo, float hi) {
    unsigned r;
    asm("v_cvt_pk_bf16_f32 %0, %1, %2" : "=v"(r) : "v"(lo), "v"(hi));
    return r;
}

// Stage a ROWSx64 bf16 tile from row-major global (stride elems) into LDS,
// XOR-swizzled: LDS slot s of row r holds global 16B-slot (s ^ (r&7)).
// global_load_lds width 16, linear LDS dest, pre-swizzled global source.
template <int ROWS, int NW>
__device__ __forceinline__ void stage_rows(const unsigned short* src, int stride,
                                           short* dst, int tid) {
    int wave = tid >> 6, lane = tid & 63;
#pragma unroll
    for (int c = 0; c < ROWS / (8 * NW); ++c) {
        int rbase = (c * NW + wave) * 8;
        int row   = rbase + (lane >> 3);
        int slot  = (lane & 7) ^ (row & 7);
        const unsigned short* g = src + (size_t)row * stride + slot * 8;
        __builtin_amdgcn_global_load_lds(
            (const __attribute__((address_space(1))) void*)g,
            (__attribute__((address_space(3))) void*)(dst + rbase * 64),
            16, 0, 0);
    }
}

// Read an MFMA A/B fragment (16 rows x 32 k) from a swizzled [ROWS][64] bf16 tile.
__device__ __forceinline__ short8 read_frag(const short* T, int rowBase, int k2) {
    int lane = threadIdx.x & 63;
    int row  = rowBase + (lane & 15);
    int slot = ((k2 * 4) + (lane >> 4)) ^ (row & 7);
    return *(const short8*)(T + row * 64 + slot * 8);
}

// ---------------- prep: fp32 -> bf16 weight conversion + h0 init ----------------
__global__ void prep_kernel(const float* __restrict__ x,
                            const float* __restrict__ gw, const float* __restrict__ tw,
                            const float* __restrict__ w0, const float* __restrict__ w1,
                            float* __restrict__ h0_f32, unsigned short* __restrict__ h0_bf,
                            unsigned short* __restrict__ wg_bf, unsigned short* __restrict__ wt_bf,
                            unsigned short* __restrict__ w0c_bf, unsigned short* __restrict__ w1_bf) {
    const int S_X = BB * NN * DD;
    const int S_W = 3 * DD * DD;
    const int S_W0 = 2 * DD * DD;
    const int S_W1 = DD * DD;
    int total = S_X + S_W + S_W + S_W0 + S_W1;
    for (int idx = blockIdx.x * blockDim.x + threadIdx.x; idx < total;
         idx += gridDim.x * blockDim.x) {
        int t = idx;
        if (t < S_X) { float v = x[t]; h0_f32[t] = v; h0_bf[t] = f2bf(v); continue; }
        t -= S_X;
        if (t < S_W) { wg_bf[t] = f2bf(gw[t]); continue; }
        t -= S_W;
        if (t < S_W) { wt_bf[t] = f2bf(tw[t]); continue; }
        t -= S_W;
        if (t < S_W0) {
            int e = t >> 9, d = t & 511;
            float v = (e < DD) ? w0[e * (2 * DD) + d] : w0[(e - DD) * (2 * DD) + DD + d];
            w0c_bf[t] = f2bf(v); continue;
        }
        t -= S_W0;
        w1_bf[t] = f2bf(w1[t]);
    }
}

// ---------------- highway layer (64x64 tiles, 4 waves, 128 blocks) ----------------
__global__ __launch_bounds__(256) void highway_kernel(
        const float* __restrict__ h_in, const unsigned short* __restrict__ hbf_in,
        const unsigned short* __restrict__ wg_bf, const unsigned short* __restrict__ wt_bf,
        const float* __restrict__ gb, const float* __restrict__ tb,
        float* __restrict__ h_out, unsigned short* __restrict__ hbf_out) {
    __shared__ short ht[64 * 64];
    __shared__ short wgt[64 * 64];
    __shared__ short wtt[64 * 64];
    int tid = threadIdx.x, lane = tid & 63, wave = tid >> 6;
    int mt = blockIdx.x >> 3, et = blockIdx.x & 7;
    int m0 = mt * 64, e0 = et * 64;
    int wm = wave >> 1, we = wave & 1;
    f32x4 gacc[2][2] = {}, tacc[2][2] = {};
    for (int ks = 0; ks < 8; ++ks) {
        int d0 = ks * 64;
        __syncthreads();
        stage_rows<64, 4>(hbf_in + (size_t)m0 * DD + d0, DD, ht, tid);
        stage_rows<64, 4>(wg_bf + (size_t)e0 * DD + d0, DD, wgt, tid);
        stage_rows<64, 4>(wt_bf + (size_t)e0 * DD + d0, DD, wtt, tid);
        __syncthreads();
#pragma unroll
        for (int k2 = 0; k2 < 2; ++k2) {
            short8 af[2], bg[2], bt[2];
#pragma unroll
            for (int f = 0; f < 2; ++f) af[f] = read_frag(ht, wm * 32 + f * 16, k2);
#pragma unroll
            for (int f = 0; f < 2; ++f) bg[f] = read_frag(wgt, we * 32 + f * 16, k2);
#pragma unroll
            for (int f = 0; f < 2; ++f) bt[f] = read_frag(wtt, we * 32 + f * 16, k2);
#pragma unroll
            for (int fm = 0; fm < 2; ++fm)
#pragma unroll
                for (int fn = 0; fn < 2; ++fn) {
                    gacc[fm][fn] = __builtin_amdgcn_mfma_f32_16x16x32_bf16(af[fm], bg[fn], gacc[fm][fn], 0, 0, 0);
                    tacc[fm][fn] = __builtin_amdgcn_mfma_f32_16x16x32_bf16(af[fm], bt[fn], tacc[fm][fn], 0, 0, 0);
                }
        }
    }
#pragma unroll
    for (int fm = 0; fm < 2; ++fm)
#pragma unroll
        for (int fn = 0; fn < 2; ++fn) {
            int e = e0 + we * 32 + fn * 16 + (lane & 15);
            float gbe = gb[e], tbe = tb[e];
#pragma unroll
            for (int r = 0; r < 4; ++r) {
                int m = m0 + wm * 32 + fm * 16 + (lane >> 4) * 4 + r;
                float g = 1.f / (1.f + __expf(-(gacc[fm][fn][r] + gbe)));
                float tv = tacc[fm][fn][r] + tbe; tv = tv > 0.f ? tv : 0.f;
                float ho = h_in[(size_t)m * DD + e];
                float hn = g * tv + (1.f - g) * ho;
                h_out[(size_t)m * DD + e] = hn;
                hbf_out[(size_t)m * DD + e] = f2bf(hn);
            }
        }
}

// ---------------- a/b projection (64x128 tiles, 4 waves, 128 blocks) ------------
__global__ __launch_bounds__(256) void ab_kernel(
        const unsigned short* __restrict__ hbf, const unsigned short* __restrict__ w0c_bf,
        const float* __restrict__ lw0_b,
        float* __restrict__ a_out, float* __restrict__ b_out) {
    __shared__ short ht[64 * 64];
    __shared__ short wt_[128 * 64];
    int tid = threadIdx.x, lane = tid & 63, wave = tid >> 6;
    int mt = blockIdx.x >> 3, et = blockIdx.x & 7;
    int m0 = mt * 64, e0 = et * 128;
    int wm = wave >> 1, we = wave & 1;
    f32x4 acc[2][4] = {};
    for (int ks = 0; ks < 8; ++ks) {
        __syncthreads();
        stage_rows<64, 4>(hbf + (size_t)m0 * DD + ks * 64, DD, ht, tid);
        stage_rows<128, 4>(w0c_bf + (size_t)e0 * DD + ks * 64, DD, wt_, tid);
        __syncthreads();
#pragma unroll
        for (int k2 = 0; k2 < 2; ++k2) {
            short8 af[2], bf_[4];
#pragma unroll
            for (int f = 0; f < 2; ++f) af[f] = read_frag(ht, wm * 32 + f * 16, k2);
#pragma unroll
            for (int f = 0; f < 4; ++f) bf_[f] = read_frag(wt_, we * 64 + f * 16, k2);
#pragma unroll
            for (int fm = 0; fm < 2; ++fm)
#pragma unroll
                for (int fn = 0; fn < 4; ++fn)
                    acc[fm][fn] = __builtin_amdgcn_mfma_f32_16x16x32_bf16(af[fm], bf_[fn], acc[fm][fn], 0, 0, 0);
        }
    }
#pragma unroll
    for (int fm = 0; fm < 2; ++fm)
#pragma unroll
        for (int fn = 0; fn < 4; ++fn) {
            int e = e0 + we * 64 + fn * 16 + (lane & 15);
#pragma unroll
            for (int r = 0; r < 4; ++r) {
                int m = m0 + wm * 32 + fm * 16 + (lane >> 4) * 4 + r;
                float v = acc[fm][fn][r];
                if (e < DD) a_out[(size_t)m * DD + e] = v + lw0_b[e];
                else        b_out[(size_t)m * DD + (e - DD)] = v;
            }
        }
}

// ---------------- fused pairwise kernel (v4: single-barrier, z-dbuf) ----------
// 8 waves, each owns 128j x 64e (all E=512, acc 32 f32x4). 8 K-steps of BK=64.
// W1 double-buffered (2x64KB) via global_load_lds, counted vmcnt(14) AFTER
// issuing next step's loads (stage stays in flight across the barrier).
// z double-buffered (2x16KB): z[k+1] computed+written during step k's MFMA
// shadow -> ONE barrier per step. setprio around MFMA phase (T5).
// LDS = 163840 B (exactly the 160KiB cap).

#define Z_LOADS(K)                                                            \
    {                                                                         \
        const int dl_ = (K) * 64 + s * 8;                                     \
        alo = *(const f32x4*)(arow + dl_);                                    \
        ahi = *(const f32x4*)(arow + dl_ + 4);                                \
        const float* b0_ = brow + (size_t)rr * DD + dl_;                      \
        const float* b1_ = brow + (size_t)(64 + rr) * DD + dl_;               \
        b0lo = *(const f32x4*)b0_; b0hi = *(const f32x4*)(b0_ + 4);           \
        b1lo = *(const f32x4*)b1_; b1hi = *(const f32x4*)(b1_ + 4);           \
    }

#define Z_MATH()                                                              \
    {                                                                         \
        zw0[0] = cvtpk(fmaxf(alo[0] + b0lo[0], 0.f), fmaxf(alo[1] + b0lo[1], 0.f)); \
        zw0[1] = cvtpk(fmaxf(alo[2] + b0lo[2], 0.f), fmaxf(alo[3] + b0lo[3], 0.f)); \
        zw0[2] = cvtpk(fmaxf(ahi[0] + b0hi[0], 0.f), fmaxf(ahi[1] + b0hi[1], 0.f)); \
        zw0[3] = cvtpk(fmaxf(ahi[2] + b0hi[2], 0.f), fmaxf(ahi[3] + b0hi[3], 0.f)); \
        zw1[0] = cvtpk(fmaxf(alo[0] + b1lo[0], 0.f), fmaxf(alo[1] + b1lo[1], 0.f)); \
        zw1[1] = cvtpk(fmaxf(alo[2] + b1lo[2], 0.f), fmaxf(alo[3] + b1lo[3], 0.f)); \
        zw1[2] = cvtpk(fmaxf(ahi[0] + b1hi[0], 0.f), fmaxf(ahi[1] + b1hi[1], 0.f)); \
        zw1[3] = cvtpk(fmaxf(ahi[2] + b1hi[2], 0.f), fmaxf(ahi[3] + b1hi[3], 0.f)); \
    }

#define Z_WRITE(BUF)                                                          \
    {                                                                         \
        *(uint32x4*)((BUF) + rr * 64 + ((s ^ (rr & 7)) * 8)) = zw0;           \
        const int r1_ = 64 + rr;                                              \
        *(uint32x4*)((BUF) + r1_ * 64 + ((s ^ (r1_ & 7)) * 8)) = zw1;         \
    }

__global__ __launch_bounds__(512, 2) void pair_kernel(
        const float* __restrict__ a_f32, const float* __restrict__ b_f32,
        const unsigned short* __restrict__ w1_bf,
        const float* __restrict__ lw1_b, const float* __restrict__ lwo_w,
        const float* __restrict__ lwo_b, float* __restrict__ out) {
    __shared__ short ws[2][512 * 64];   // 128KB W1 double buffer
    __shared__ short zs[2][128 * 64];   // 32KB z double buffer; s_red alias after loop
    int tid = threadIdx.x, lane = tid & 63, wave = tid >> 6;
    int bid = blockIdx.x;
    // bijective XCD swizzle: each XCD's blocks cover a contiguous i-range
    int swz = (bid & 7) * 256 + (bid >> 3);
    int bb = swz >> 9, i = (swz >> 1) & 255, j0 = (swz & 1) * 128;
    const float* arow = a_f32 + (size_t)(bb * NN + i) * DD;
    const float* brow = b_f32 + (size_t)(bb * NN + j0) * DD;
    int s = tid & 7, rr = tid >> 3;     // z producer coords (rr: 0..63)
    int we = wave;                       // e-slice owner: e in [we*64, we*64+64)

    f32x4 acc[8][4] = {};
    uint32x4 zw0, zw1;
    f32x4 alo, ahi, b0lo, b0hi, b1lo, b1hi;

    // ---- prologue: z[0] + W1[0] stage ----
    Z_LOADS(0)
    stage_rows<512, 8>(w1_bf, DD, ws[0], tid);
    Z_MATH()
    Z_WRITE(zs[0])
    asm volatile("s_waitcnt lgkmcnt(0)" ::: "memory");

#pragma unroll
    for (int k = 0; k < 8; ++k) {
        __builtin_amdgcn_s_barrier();    // zs[k&1] visible; ws[k&1] pending vmcnt
        __builtin_amdgcn_sched_barrier(0);
        if (k < 7) {
            Z_LOADS(k + 1)               // 6 vm loads (consumed after MFMA)
            stage_rows<512, 8>(w1_bf + (size_t)(k + 1) * 64, DD, ws[(k + 1) & 1], tid); // 8 vm
            asm volatile("s_waitcnt vmcnt(14)" ::: "memory");  // drain stage(k); keep 14 in flight
        } else {
            asm volatile("s_waitcnt vmcnt(0)" ::: "memory");
        }
        __builtin_amdgcn_sched_barrier(0);

        const short* zc = zs[k & 1];
        const short* wc = ws[k & 1];
        __builtin_amdgcn_s_setprio(1);
#pragma unroll
        for (int k2 = 0; k2 < 2; ++k2) {
            short8 bfr[4];
#pragma unroll
            for (int f = 0; f < 4; ++f) bfr[f] = read_frag(wc, we * 64 + f * 16, k2);
#pragma unroll
            for (int fh = 0; fh < 2; ++fh) {
                short8 af[4];
#pragma unroll
                for (int f = 0; f < 4; ++f) af[f] = read_frag(zc, (fh * 4 + f) * 16, k2);
#pragma unroll
                for (int fm = 0; fm < 4; ++fm)
#pragma unroll
                    for (int fn = 0; fn < 4; ++fn)
                        acc[fh * 4 + fm][fn] = __builtin_amdgcn_mfma_f32_16x16x32_bf16(
                            af[fm], bfr[fn], acc[fh * 4 + fm][fn], 0, 0, 0);
            }
        }
        __builtin_amdgcn_s_setprio(0);

        if (k < 7) {
            Z_MATH()                     // z[k+1], under MFMA drain
            Z_WRITE(zs[(k + 1) & 1])
            asm volatile("s_waitcnt lgkmcnt(0)" ::: "memory");  // own writes done pre-barrier
        }
    }

    // ---- epilogue: relu(acc+b1)*wo, reduce over all e ----
    __syncthreads();                     // all zs reads done -> alias as s_red
    float* s_red = (float*)zs;           // 8 waves x 128 j partials
#pragma unroll
    for (int fm = 0; fm < 8; ++fm) {
        float red[4] = {0.f, 0.f, 0.f, 0.f};
#pragma unroll
        for (int fn = 0; fn < 4; ++fn) {
            int e = we * 64 + fn * 16 + (lane & 15);
            float b1e = lw1_b[e], woe = lwo_w[e];
#pragma unroll
            for (int r = 0; r < 4; ++r) {
                float v = acc[fm][fn][r] + b1e;
                red[r] += (v > 0.f) ? v * woe : 0.f;
            }
        }
#pragma unroll
        for (int mask = 1; mask < 16; mask <<= 1)
#pragma unroll
            for (int r = 0; r < 4; ++r) red[r] += __shfl_xor(red[r], mask, 64);
        if ((lane & 15) == 0) {
#pragma unroll
            for (int r = 0; r < 4; ++r)
                s_red[we * 128 + fm * 16 + (lane >> 4) * 4 + r] = red[r];
        }
    }
    __syncthreads();
    if (tid < 128) {
        float v = lwo_b[0];
#pragma unroll
        for (int w8 = 0; w8 < 8; ++w8) v += s_red[w8 * 128 + tid];
        out[((size_t)(bb * NN + i)) * NN + j0 + tid] = 1.f / (1.f + __expf(-v));
    }
}

extern "C" void kernel_launch(void* const* d_in, const int* in_sizes, int n_in,
                              void* d_out, int out_size, void* d_ws, size_t ws_size,
                              hipStream_t stream) {
    const float* x    = (const float*)d_in[0];
    const float* gw   = (const float*)d_in[1];
    const float* gb   = (const float*)d_in[2];
    const float* tw   = (const float*)d_in[3];
    const float* tb   = (const float*)d_in[4];
    const float* w0   = (const float*)d_in[5];
    const float* w0b  = (const float*)d_in[6];
    const float* w1   = (const float*)d_in[7];
    const float* w1b_ = (const float*)d_in[8];
    const float* wo   = (const float*)d_in[9];
    const float* wob  = (const float*)d_in[10];
    float* out = (float*)d_out;

    char* w = (char*)d_ws;
    float* hA  = (float*)w;            w += (size_t)BB * NN * DD * 4;
    float* hB  = (float*)w;            w += (size_t)BB * NN * DD * 4;
    unsigned short* hbA = (unsigned short*)w; w += (size_t)BB * NN * DD * 2;
    unsigned short* hbB = (unsigned short*)w; w += (size_t)BB * NN * DD * 2;
    float* a_f = (float*)w;            w += (size_t)BB * NN * DD * 4;
    float* b_f = (float*)w;            w += (size_t)BB * NN * DD * 4;
    unsigned short* wg_bf  = (unsigned short*)w; w += (size_t)3 * DD * DD * 2;
    unsigned short* wt_bf  = (unsigned short*)w; w += (size_t)3 * DD * DD * 2;
    unsigned short* w0c_bf = (unsigned short*)w; w += (size_t)2 * DD * DD * 2;
    unsigned short* w1_bf  = (unsigned short*)w; w += (size_t)DD * DD * 2;

    prep_kernel<<<1024, 256, 0, stream>>>(x, gw, tw, w0, w1, hA, hbA, wg_bf, wt_bf, w0c_bf, w1_bf);

    highway_kernel<<<128, 256, 0, stream>>>(hA, hbA, wg_bf + 0 * DD * DD, wt_bf + 0 * DD * DD,
                                            gb + 0 * DD, tb + 0 * DD, hB, hbB);
    highway_kernel<<<128, 256, 0, stream>>>(hB, hbB, wg_bf + 1 * DD * DD, wt_bf + 1 * DD * DD,
                                            gb + 1 * DD, tb + 1 * DD, hA, hbA);
    highway_kernel<<<128, 256, 0, stream>>>(hA, hbA, wg_bf + 2 * DD * DD, wt_bf + 2 * DD * DD,
                                            gb + 2 * DD, tb + 2 * DD, hB, hbB);

    ab_kernel<<<128, 256, 0, stream>>>(hbB, w0c_bf, w0b, a_f, b_f);

    pair_kernel<<<2048, 512, 0, stream>>>(a_f, b_f, w1_bf, w1b_, wo, wob, out);
}